// Round 14
// baseline (189.578 us; speedup 1.0000x reference)
//
#include <hip/hip_runtime.h>

// 2-layer GCN, padded-CSR gather + bf16-MFMA, 4 stream-ordered dispatches.
//
// LESSON (R6-R8, measured): grid.sync() costs ~250-300us EACH on MI355X
// (cross-XCD L2 writeback/invalidate). Do NOT fuse phases with grid.sync.
// LESSON (R9): mean degree 16 -- hide gather latency via INDEPENDENT chains
// (quarter-wave-per-node), not unroll depth.
// LESSON (R12): padded CSR (64 slots/node) kills the prefix scan.
// LESSON (R13): k_gcn1 is LATENCY-bound (84MB L2-miss @1.8TB/s, occ 40%
// under (256,4)); its measured VGPR=48 fits (256,8)'s 64-reg budget ->
// raise occupancy for 2x outstanding loads. R6's spill was the mega-kernel's
// extra state, NOT this body. Also: rank-store and csrp-scatter have the SAME
// atomic-return dependency -- fuse scatter into the atomic pass, drop k_fill.
//
//   memset : deg
//   k_rank : pos=atomicAdd(deg[dst],1); csrp[dst*64+pos]=src  (fused scatter)
//            | xb=bf16(x) | W1 -> bf16 B-fragment pack | b1/W2 pad
//   k_gcn1 : per 16-node tile: gather A[n]=dinv_n*(sum w_s*xb[s] + dinv_n*xb[n]),
//            zd = dinv * ( relu(A@W1 + b1) @ W2 ) via mfma_f32_16x16x32_bf16
//   k_gz   : out[i] = dinv[i]*(sum_{s in N(i)} zd[s] + zd[i]) + b2

#define N_NODES 50000
#define N_EDGES 800000
#define D_FEAT  128
#define D_HID   500
#define NTILES  3125         // 50000 / 16
#define RB      782          // ceil(800000 / (256*4)) atomic blocks
#define XB      1563         // ceil(1,600,000 float4 / (256*4)) convert blocks
#define CSTRIDE 64           // padded CSR slots per node

typedef __bf16 bf16x8 __attribute__((ext_vector_type(8)));
typedef float  f32x4  __attribute__((ext_vector_type(4)));

static __device__ inline unsigned int f2bf(float f) {   // fp32 -> bf16 bits, RTNE
    unsigned int u = __float_as_uint(f);
    return (u + 0x7fffu + ((u >> 16) & 1u)) >> 16;
}
static __device__ inline float bf_lo(unsigned int u) { return __uint_as_float(u << 16); }
static __device__ inline float bf_hi(unsigned int u) { return __uint_as_float(u & 0xffff0000u); }

static __device__ inline void fma8(float* acc, uint4 u, float w) {
    acc[0] = fmaf(w, bf_lo(u.x), acc[0]);
    acc[1] = fmaf(w, bf_hi(u.x), acc[1]);
    acc[2] = fmaf(w, bf_lo(u.y), acc[2]);
    acc[3] = fmaf(w, bf_hi(u.y), acc[3]);
    acc[4] = fmaf(w, bf_lo(u.z), acc[4]);
    acc[5] = fmaf(w, bf_hi(u.z), acc[5]);
    acc[6] = fmaf(w, bf_lo(u.w), acc[6]);
    acc[7] = fmaf(w, bf_hi(u.w), acc[7]);
}

// ---- k_rank: [0,RB) atomic+scatter | [RB,RB+XB) x->bf16 | 32 pack | 1 pad
__global__ __launch_bounds__(256) void k_rank(const int* __restrict__ src,
                                              const int* __restrict__ dst,
                                              const float* __restrict__ x,
                                              const float* __restrict__ W1,
                                              const float* __restrict__ b1,
                                              const float* __restrict__ W2,
                                              int* __restrict__ deg,
                                              int* __restrict__ csrp,
                                              uint2* __restrict__ xb,
                                              unsigned short* __restrict__ b_pk,
                                              float* __restrict__ b1p,
                                              float* __restrict__ w2p) {
    const int b = blockIdx.x, tid = threadIdx.x;
    if (b < RB) {                                     // 4 independent atomic+scatter chains
        int t4 = b * 256 + tid;
        if (t4 < N_EDGES / 4) {
            int e = t4 * 4;
            int4 d4 = *(const int4*)&dst[e];
            int4 s4 = *(const int4*)&src[e];
            int p0 = atomicAdd(&deg[d4.x], 1);
            int p1 = atomicAdd(&deg[d4.y], 1);
            int p2 = atomicAdd(&deg[d4.z], 1);
            int p3 = atomicAdd(&deg[d4.w], 1);
            if (p0 < CSTRIDE) csrp[d4.x * CSTRIDE + p0] = s4.x;  // P(deg>64)~0 guard
            if (p1 < CSTRIDE) csrp[d4.y * CSTRIDE + p1] = s4.y;
            if (p2 < CSTRIDE) csrp[d4.z * CSTRIDE + p2] = s4.z;
            if (p3 < CSTRIDE) csrp[d4.w * CSTRIDE + p3] = s4.w;
        }
    } else if (b < RB + XB) {                         // xb = bf16(x), 4 float4/thread
        const int base = (b - RB) * 1024;
#pragma unroll
        for (int j = 0; j < 4; j++) {
            int i = base + j * 256 + tid;             // coalesced sweeps
            if (i < N_NODES * D_FEAT / 4) {
                float4 v = ((const float4*)x)[i];
                uint2 o;
                o.x = f2bf(v.x) | (f2bf(v.y) << 16);
                o.y = f2bf(v.z) | (f2bf(v.w) << 16);
                xb[i] = o;
            }
        }
    } else if (b < RB + XB + 32) {                    // W1 -> B-fragment pack
        int idx  = (b - RB - XB) * 256 + tid;         // [0, 8192)
        int lane = idx & 63;
        int slot = idx >> 6;
        int t    = slot >> 2;                         // n-tile
        int ks   = slot & 3;                          // k-step
        int quad = lane >> 4;
        int n    = t * 16 + (lane & 15);
        unsigned int us[8];
#pragma unroll
        for (int j = 0; j < 8; j++) {
            int k = ks * 32 + quad * 8 + j;
            float v = (n < D_HID) ? W1[(size_t)k * D_HID + n] : 0.f;
            us[j] = f2bf(v);
        }
        uint4 p;
        p.x = us[0] | (us[1] << 16);
        p.y = us[2] | (us[3] << 16);
        p.z = us[4] | (us[5] << 16);
        p.w = us[6] | (us[7] << 16);
        ((uint4*)b_pk)[idx] = p;
    } else {                                          // pad b1 / W2 to 512
        for (int i = tid; i < 512; i += 256) {
            b1p[i] = (i < D_HID) ? b1[i] : 0.f;
            w2p[i] = (i < D_HID) ? W2[i] : 0.f;
        }
    }
}

// Fused gather + bf16-MFMA MLP. Block = 16 nodes, 4 waves. Gather is
// QUARTER-WAVE-PER-NODE: 16 lanes own one node; lane p holds 16B of the row;
// 4-edge unroll -> 4 independent (deg,row) load pairs in flight per quarter.
// (256,8): body measured at 48 VGPR -- fits the 64-reg budget; 8 blocks/CU
// doubles outstanding loads for this latency-bound gather (R13 occ was 40%).
__global__ __launch_bounds__(256, 8) void k_gcn1(const uint4* __restrict__ xb4,
                                                 const int* __restrict__ csrp,
                                                 const int* __restrict__ deg,
                                                 const unsigned short* __restrict__ b_pk,
                                                 const float* __restrict__ b1p,
                                                 const float* __restrict__ w2p,
                                                 float* __restrict__ zd) {
    __shared__ unsigned short A[16][136];   // bf16 rows; 272B stride, 2-way alias = free
    __shared__ float red[4][16];
    const int t = threadIdx.x;
    const int node0 = blockIdx.x * 16;      // 50000 = 16 * 3125
    const int wv = t >> 6, lane = t & 63;
    const int q = lane >> 4, p = lane & 15;

    // ---- Phase 1: gather; quarter q of wave wv owns node n = wv*4+q ----
    {
        const int n = wv * 4 + q;
        const int node = node0 + n;
        int dg = deg[node];
        if (dg > CSTRIDE) dg = CSTRIDE;     // never fires; memory-safety guard
        const int base = node * CSTRIDE;
        float acc[8];
#pragma unroll
        for (int j = 0; j < 8; j++) acc[j] = 0.f;

        int e = 0;
        for (; e + 4 <= dg; e += 4) {       // 1 int4 index load + 4 (deg,row) pairs
            int4 s4 = *(const int4*)&csrp[base + e];
            int g0 = deg[s4.x], g1 = deg[s4.y], g2 = deg[s4.z], g3 = deg[s4.w];
            uint4 u0 = xb4[(size_t)s4.x * 16 + p];
            uint4 u1 = xb4[(size_t)s4.y * 16 + p];
            uint4 u2 = xb4[(size_t)s4.z * 16 + p];
            uint4 u3 = xb4[(size_t)s4.w * 16 + p];
            fma8(acc, u0, rsqrtf((float)(g0 + 1)));
            fma8(acc, u1, rsqrtf((float)(g1 + 1)));
            fma8(acc, u2, rsqrtf((float)(g2 + 1)));
            fma8(acc, u3, rsqrtf((float)(g3 + 1)));
        }
        for (; e < dg; e++) {
            int s = csrp[base + e];
            int g = deg[s];
            uint4 u = xb4[(size_t)s * 16 + p];
            fma8(acc, u, rsqrtf((float)(g + 1)));
        }

        // self-loop + finalize: A[n] = bf16( di * (acc + di*xb[node]) )
        const float di = rsqrtf((float)(dg + 1));
        uint4 su = xb4[(size_t)node * 16 + p];
        uint4 o;
        o.x = f2bf(di * (acc[0] + di * bf_lo(su.x))) |
              (f2bf(di * (acc[1] + di * bf_hi(su.x))) << 16);
        o.y = f2bf(di * (acc[2] + di * bf_lo(su.y))) |
              (f2bf(di * (acc[3] + di * bf_hi(su.y))) << 16);
        o.z = f2bf(di * (acc[4] + di * bf_lo(su.z))) |
              (f2bf(di * (acc[5] + di * bf_hi(su.z))) << 16);
        o.w = f2bf(di * (acc[6] + di * bf_lo(su.w))) |
              (f2bf(di * (acc[7] + di * bf_hi(su.w))) << 16);
        *(uint4*)&A[n][p * 8] = o;
    }
    __syncthreads();

    // ---- Phase 2: D[16][512] via 16x16x32 bf16 MFMA; wave owns 8 n-tiles ----
    bf16x8 afr[4];
#pragma unroll
    for (int ks = 0; ks < 4; ks++)
        afr[ks] = *(const bf16x8*)&A[p][ks * 32 + q * 8];

    const bf16x8* __restrict__ bpk = (const bf16x8*)b_pk;
    f32x4 acc[8];
#pragma unroll
    for (int tt = 0; tt < 8; tt++) acc[tt] = (f32x4){0.f, 0.f, 0.f, 0.f};
#pragma unroll
    for (int tt = 0; tt < 8; tt++) {
        const int tile_n = wv * 8 + tt;
#pragma unroll
        for (int ks = 0; ks < 4; ks++) {
            bf16x8 bfr = bpk[(size_t)(tile_n * 4 + ks) * 64 + lane];
            acc[tt] = __builtin_amdgcn_mfma_f32_16x16x32_bf16(afr[ks], bfr, acc[tt], 0, 0, 0);
        }
    }

    // epilogue: zd-partial = relu(D + b1) . W2   (C/D: col=p, row=q*4+r)
    float zp[4] = {0.f, 0.f, 0.f, 0.f};
#pragma unroll
    for (int tt = 0; tt < 8; tt++) {
        const int c = (wv * 8 + tt) * 16 + p;
        const float b1v = b1p[c];
        const float w2v = w2p[c];
#pragma unroll
        for (int r = 0; r < 4; r++)
            zp[r] += fmaxf(acc[tt][r] + b1v, 0.f) * w2v;
    }
#pragma unroll
    for (int off = 1; off < 16; off <<= 1) {
#pragma unroll
        for (int r = 0; r < 4; r++) zp[r] += __shfl_xor(zp[r], off);
    }
    if (p == 0) {
#pragma unroll
        for (int r = 0; r < 4; r++) red[wv][q * 4 + r] = zp[r];
    }
    __syncthreads();
    if (t < 16) {
        int node = node0 + t;
        float zz = red[0][t] + red[1][t] + red[2][t] + red[3][t];
        zd[node] = rsqrtf((float)(deg[node] + 1)) * zz;
    }
}

// Layer-2 scalar gather: 16 lanes per node, shuffle-reduce (zd 200KB, L2-hot).
__global__ __launch_bounds__(256) void k_gz(const int* __restrict__ csrp,
                                            const int* __restrict__ deg,
                                            const float* __restrict__ zd,
                                            const float* __restrict__ b2,
                                            float* __restrict__ out) {
    const int node = blockIdx.x * 16 + (threadIdx.x >> 4);
    const int l = threadIdx.x & 15;
    int dg = deg[node];
    if (dg > CSTRIDE) dg = CSTRIDE;
    const int base = node * CSTRIDE;
    float s = 0.f;
    for (int e = l; e < dg; e += 16) s += zd[csrp[base + e]];
#pragma unroll
    for (int off = 1; off < 16; off <<= 1) s += __shfl_xor(s, off);
    if (l == 0) {
        float di = rsqrtf((float)(dg + 1));
        out[node] = di * (s + zd[node]) + b2[0];
    }
}

extern "C" void kernel_launch(void* const* d_in, const int* in_sizes, int n_in,
                              void* d_out, int out_size, void* d_ws, size_t ws_size,
                              hipStream_t stream) {
    const float* x  = (const float*)d_in[0];
    const int*   ei = (const int*)d_in[1];     // [2, E]: row 0 = src, row 1 = dst
    const float* W1 = (const float*)d_in[2];
    const float* b1 = (const float*)d_in[3];
    const float* W2 = (const float*)d_in[4];
    const float* b2 = (const float*)d_in[5];
    float* out = (float*)d_out;

    const int* src = ei;
    const int* dst = ei + N_EDGES;

    // Workspace layout (~26.2 MB).
    uint2* xb            = (uint2*)d_ws;                       // 1,600,000 uint2 (12.8 MB)
    unsigned short* b_pk = (unsigned short*)(xb + 1600000);    // 65,536 bf16 (128 KB)
    float* b1p    = (float*)(b_pk + 65536);                    // 512
    float* w2p    = b1p + 512;                                 // 512
    float* zd     = w2p + 512;                                 // 50000
    int* deg      = (int*)(zd + N_NODES);                      // 50000
    int* csrp     = deg + N_NODES;                             // 3,200,000 (12.8 MB)

    hipMemsetAsync(deg, 0, N_NODES * sizeof(int), stream);

    k_rank<<<RB + XB + 33, 256, 0, stream>>>(src, dst, x, W1, b1, W2, deg,
                                             csrp, xb, b_pk, b1p, w2p);
    k_gcn1<<<NTILES, 256, 0, stream>>>((const uint4*)xb, csrp, deg,
                                       b_pk, b1p, w2p, zd);
    k_gz  <<<NTILES, 256, 0, stream>>>(csrp, deg, zd, b2, out);
}

// Round 15
// 178.778 us; speedup vs baseline: 1.0604x; 1.0604x over previous
//
#include <hip/hip_runtime.h>

// 2-layer GCN, padded-CSR gather + bf16-MFMA, 5 stream-ordered dispatches.
//
// LESSON (R6-R8, measured): grid.sync() costs ~250-300us EACH on MI355X.
// Do NOT fuse phases with grid.sync.
// LESSON (R9): mean degree 16 -- hide gather latency via INDEPENDENT chains
// (quarter-wave-per-node), not unroll depth.
// LESSON (R12): padded CSR (64 slots/node) kills the prefix scan.
// LESSON (R13/R14, measured): (256,8) on k_gcn1 helps (latency-bound gather,
// 48 VGPR fits the 64-reg budget). But fusing the csrp scatter into the
// atomic pass regressed: 51MB of random 4B stores + address-dependency on the
// atomic return made k_rank 73us/61MB-write. Keep rank fire-and-forget
// (3.2MB coalesced) and the scatter in its own atomic-free pass.
//
//   memset : deg
//   k_rank : rank[e]=atomicAdd(deg[dst],1) 8 edges/thread (fire-and-forget)
//            | xb=bf16(x) | W1 -> bf16 B-fragment pack | b1/W2 pad
//   k_fill : csrp[dst*64+rank] = src   (no atomics, 4 edges/thread)
//   k_gcn1 : per 16-node tile: gather A[n]=dinv_n*(sum w_s*xb[s] + dinv_n*xb[n]),
//            zd = dinv * ( relu(A@W1 + b1) @ W2 ) via mfma_f32_16x16x32_bf16
//   k_gz   : out[i] = dinv[i]*(sum_{s in N(i)} zd[s] + zd[i]) + b2

#define N_NODES 50000
#define N_EDGES 800000
#define D_FEAT  128
#define D_HID   500
#define NTILES  3125         // 50000 / 16
#define RB8     391          // ceil(800000 / (256*8)) atomic blocks
#define FB      782          // ceil(800000 / (256*4)) fill blocks
#define XB      1563         // ceil(1,600,000 float4 / (256*4)) convert blocks
#define CSTRIDE 64           // padded CSR slots per node

typedef __bf16 bf16x8 __attribute__((ext_vector_type(8)));
typedef float  f32x4  __attribute__((ext_vector_type(4)));

static __device__ inline unsigned int f2bf(float f) {   // fp32 -> bf16 bits, RTNE
    unsigned int u = __float_as_uint(f);
    return (u + 0x7fffu + ((u >> 16) & 1u)) >> 16;
}
static __device__ inline float bf_lo(unsigned int u) { return __uint_as_float(u << 16); }
static __device__ inline float bf_hi(unsigned int u) { return __uint_as_float(u & 0xffff0000u); }

static __device__ inline void fma8(float* acc, uint4 u, float w) {
    acc[0] = fmaf(w, bf_lo(u.x), acc[0]);
    acc[1] = fmaf(w, bf_hi(u.x), acc[1]);
    acc[2] = fmaf(w, bf_lo(u.y), acc[2]);
    acc[3] = fmaf(w, bf_hi(u.y), acc[3]);
    acc[4] = fmaf(w, bf_lo(u.z), acc[4]);
    acc[5] = fmaf(w, bf_hi(u.z), acc[5]);
    acc[6] = fmaf(w, bf_lo(u.w), acc[6]);
    acc[7] = fmaf(w, bf_hi(u.w), acc[7]);
}

// ---- k_rank: [0,RB8) atomic rank (8/thread) | [RB8,RB8+XB) x->bf16 |
// ---- 32 W1-pack blocks | 1 pad block ----
__global__ __launch_bounds__(256) void k_rank(const int* __restrict__ dst,
                                              const float* __restrict__ x,
                                              const float* __restrict__ W1,
                                              const float* __restrict__ b1,
                                              const float* __restrict__ W2,
                                              int* __restrict__ deg,
                                              int* __restrict__ rank,
                                              uint2* __restrict__ xb,
                                              unsigned short* __restrict__ b_pk,
                                              float* __restrict__ b1p,
                                              float* __restrict__ w2p) {
    const int b = blockIdx.x, tid = threadIdx.x;
    if (b < RB8) {                                    // 8 independent atomics in flight
        int t8 = b * 256 + tid;
        if (t8 < N_EDGES / 8) {
            int e = t8 * 8;
            int4 da = *(const int4*)&dst[e];
            int4 db = *(const int4*)&dst[e + 4];
            int4 ra, rb;
            ra.x = atomicAdd(&deg[da.x], 1);
            ra.y = atomicAdd(&deg[da.y], 1);
            ra.z = atomicAdd(&deg[da.z], 1);
            ra.w = atomicAdd(&deg[da.w], 1);
            rb.x = atomicAdd(&deg[db.x], 1);
            rb.y = atomicAdd(&deg[db.y], 1);
            rb.z = atomicAdd(&deg[db.z], 1);
            rb.w = atomicAdd(&deg[db.w], 1);
            *(int4*)&rank[e]     = ra;                // coalesced, fire-and-forget
            *(int4*)&rank[e + 4] = rb;
        }
    } else if (b < RB8 + XB) {                        // xb = bf16(x), 4 float4/thread
        const int base = (b - RB8) * 1024;
#pragma unroll
        for (int j = 0; j < 4; j++) {
            int i = base + j * 256 + tid;             // coalesced sweeps
            if (i < N_NODES * D_FEAT / 4) {
                float4 v = ((const float4*)x)[i];
                uint2 o;
                o.x = f2bf(v.x) | (f2bf(v.y) << 16);
                o.y = f2bf(v.z) | (f2bf(v.w) << 16);
                xb[i] = o;
            }
        }
    } else if (b < RB8 + XB + 32) {                   // W1 -> B-fragment pack
        int idx  = (b - RB8 - XB) * 256 + tid;        // [0, 8192)
        int lane = idx & 63;
        int slot = idx >> 6;
        int t    = slot >> 2;                         // n-tile
        int ks   = slot & 3;                          // k-step
        int quad = lane >> 4;
        int n    = t * 16 + (lane & 15);
        unsigned int us[8];
#pragma unroll
        for (int j = 0; j < 8; j++) {
            int k = ks * 32 + quad * 8 + j;
            float v = (n < D_HID) ? W1[(size_t)k * D_HID + n] : 0.f;
            us[j] = f2bf(v);
        }
        uint4 p;
        p.x = us[0] | (us[1] << 16);
        p.y = us[2] | (us[3] << 16);
        p.z = us[4] | (us[5] << 16);
        p.w = us[6] | (us[7] << 16);
        ((uint4*)b_pk)[idx] = p;
    } else {                                          // pad b1 / W2 to 512
        for (int i = tid; i < 512; i += 256) {
            b1p[i] = (i < D_HID) ? b1[i] : 0.f;
            w2p[i] = (i < D_HID) ? W2[i] : 0.f;
        }
    }
}

// Atomic-free padded-CSR scatter, 4 edges/thread.
__global__ __launch_bounds__(256) void k_fill(const int* __restrict__ src,
                                              const int* __restrict__ dst,
                                              const int* __restrict__ rank,
                                              int* __restrict__ csrp) {
    int t4 = blockIdx.x * 256 + threadIdx.x;
    if (t4 >= N_EDGES / 4) return;
    int e = t4 * 4;
    int4 s4 = *(const int4*)&src[e];
    int4 d4 = *(const int4*)&dst[e];
    int4 r4 = *(const int4*)&rank[e];
    if (r4.x < CSTRIDE) csrp[d4.x * CSTRIDE + r4.x] = s4.x;   // P(deg>64)~0 guard
    if (r4.y < CSTRIDE) csrp[d4.y * CSTRIDE + r4.y] = s4.y;
    if (r4.z < CSTRIDE) csrp[d4.z * CSTRIDE + r4.z] = s4.z;
    if (r4.w < CSTRIDE) csrp[d4.w * CSTRIDE + r4.w] = s4.w;
}

// Fused gather + bf16-MFMA MLP. Block = 16 nodes, 4 waves. Gather is
// QUARTER-WAVE-PER-NODE: 16 lanes own one node; lane p holds 16B of the row;
// 4-edge unroll -> 4 independent (deg,row) load pairs in flight per quarter.
// (256,8): body is 48 VGPR, fits 64-reg budget; 8 blocks/CU doubles
// outstanding loads (R14: everything-but-k_rank dropped ~14us vs R13).
__global__ __launch_bounds__(256, 8) void k_gcn1(const uint4* __restrict__ xb4,
                                                 const int* __restrict__ csrp,
                                                 const int* __restrict__ deg,
                                                 const unsigned short* __restrict__ b_pk,
                                                 const float* __restrict__ b1p,
                                                 const float* __restrict__ w2p,
                                                 float* __restrict__ zd) {
    __shared__ unsigned short A[16][136];   // bf16 rows; 272B stride, 2-way alias = free
    __shared__ float red[4][16];
    const int t = threadIdx.x;
    const int node0 = blockIdx.x * 16;      // 50000 = 16 * 3125
    const int wv = t >> 6, lane = t & 63;
    const int q = lane >> 4, p = lane & 15;

    // ---- Phase 1: gather; quarter q of wave wv owns node n = wv*4+q ----
    {
        const int n = wv * 4 + q;
        const int node = node0 + n;
        int dg = deg[node];
        if (dg > CSTRIDE) dg = CSTRIDE;     // never fires; memory-safety guard
        const int base = node * CSTRIDE;
        float acc[8];
#pragma unroll
        for (int j = 0; j < 8; j++) acc[j] = 0.f;

        int e = 0;
        for (; e + 4 <= dg; e += 4) {       // 1 int4 index load + 4 (deg,row) pairs
            int4 s4 = *(const int4*)&csrp[base + e];
            int g0 = deg[s4.x], g1 = deg[s4.y], g2 = deg[s4.z], g3 = deg[s4.w];
            uint4 u0 = xb4[(size_t)s4.x * 16 + p];
            uint4 u1 = xb4[(size_t)s4.y * 16 + p];
            uint4 u2 = xb4[(size_t)s4.z * 16 + p];
            uint4 u3 = xb4[(size_t)s4.w * 16 + p];
            fma8(acc, u0, rsqrtf((float)(g0 + 1)));
            fma8(acc, u1, rsqrtf((float)(g1 + 1)));
            fma8(acc, u2, rsqrtf((float)(g2 + 1)));
            fma8(acc, u3, rsqrtf((float)(g3 + 1)));
        }
        for (; e < dg; e++) {
            int s = csrp[base + e];
            int g = deg[s];
            uint4 u = xb4[(size_t)s * 16 + p];
            fma8(acc, u, rsqrtf((float)(g + 1)));
        }

        // self-loop + finalize: A[n] = bf16( di * (acc + di*xb[node]) )
        const float di = rsqrtf((float)(dg + 1));
        uint4 su = xb4[(size_t)node * 16 + p];
        uint4 o;
        o.x = f2bf(di * (acc[0] + di * bf_lo(su.x))) |
              (f2bf(di * (acc[1] + di * bf_hi(su.x))) << 16);
        o.y = f2bf(di * (acc[2] + di * bf_lo(su.y))) |
              (f2bf(di * (acc[3] + di * bf_hi(su.y))) << 16);
        o.z = f2bf(di * (acc[4] + di * bf_lo(su.z))) |
              (f2bf(di * (acc[5] + di * bf_hi(su.z))) << 16);
        o.w = f2bf(di * (acc[6] + di * bf_lo(su.w))) |
              (f2bf(di * (acc[7] + di * bf_hi(su.w))) << 16);
        *(uint4*)&A[n][p * 8] = o;
    }
    __syncthreads();

    // ---- Phase 2: D[16][512] via 16x16x32 bf16 MFMA; wave owns 8 n-tiles ----
    bf16x8 afr[4];
#pragma unroll
    for (int ks = 0; ks < 4; ks++)
        afr[ks] = *(const bf16x8*)&A[p][ks * 32 + q * 8];

    const bf16x8* __restrict__ bpk = (const bf16x8*)b_pk;
    f32x4 acc[8];
#pragma unroll
    for (int tt = 0; tt < 8; tt++) acc[tt] = (f32x4){0.f, 0.f, 0.f, 0.f};
#pragma unroll
    for (int tt = 0; tt < 8; tt++) {
        const int tile_n = wv * 8 + tt;
#pragma unroll
        for (int ks = 0; ks < 4; ks++) {
            bf16x8 bfr = bpk[(size_t)(tile_n * 4 + ks) * 64 + lane];
            acc[tt] = __builtin_amdgcn_mfma_f32_16x16x32_bf16(afr[ks], bfr, acc[tt], 0, 0, 0);
        }
    }

    // epilogue: zd-partial = relu(D + b1) . W2   (C/D: col=p, row=q*4+r)
    float zp[4] = {0.f, 0.f, 0.f, 0.f};
#pragma unroll
    for (int tt = 0; tt < 8; tt++) {
        const int c = (wv * 8 + tt) * 16 + p;
        const float b1v = b1p[c];
        const float w2v = w2p[c];
#pragma unroll
        for (int r = 0; r < 4; r++)
            zp[r] += fmaxf(acc[tt][r] + b1v, 0.f) * w2v;
    }
#pragma unroll
    for (int off = 1; off < 16; off <<= 1) {
#pragma unroll
        for (int r = 0; r < 4; r++) zp[r] += __shfl_xor(zp[r], off);
    }
    if (p == 0) {
#pragma unroll
        for (int r = 0; r < 4; r++) red[wv][q * 4 + r] = zp[r];
    }
    __syncthreads();
    if (t < 16) {
        int node = node0 + t;
        float zz = red[0][t] + red[1][t] + red[2][t] + red[3][t];
        zd[node] = rsqrtf((float)(deg[node] + 1)) * zz;
    }
}

// Layer-2 scalar gather: 16 lanes per node, shuffle-reduce (zd 200KB, L2-hot).
__global__ __launch_bounds__(256) void k_gz(const int* __restrict__ csrp,
                                            const int* __restrict__ deg,
                                            const float* __restrict__ zd,
                                            const float* __restrict__ b2,
                                            float* __restrict__ out) {
    const int node = blockIdx.x * 16 + (threadIdx.x >> 4);
    const int l = threadIdx.x & 15;
    int dg = deg[node];
    if (dg > CSTRIDE) dg = CSTRIDE;
    const int base = node * CSTRIDE;
    float s = 0.f;
    for (int e = l; e < dg; e += 16) s += zd[csrp[base + e]];
#pragma unroll
    for (int off = 1; off < 16; off <<= 1) s += __shfl_xor(s, off);
    if (l == 0) {
        float di = rsqrtf((float)(dg + 1));
        out[node] = di * (s + zd[node]) + b2[0];
    }
}

extern "C" void kernel_launch(void* const* d_in, const int* in_sizes, int n_in,
                              void* d_out, int out_size, void* d_ws, size_t ws_size,
                              hipStream_t stream) {
    const float* x  = (const float*)d_in[0];
    const int*   ei = (const int*)d_in[1];     // [2, E]: row 0 = src, row 1 = dst
    const float* W1 = (const float*)d_in[2];
    const float* b1 = (const float*)d_in[3];
    const float* W2 = (const float*)d_in[4];
    const float* b2 = (const float*)d_in[5];
    float* out = (float*)d_out;

    const int* src = ei;
    const int* dst = ei + N_EDGES;

    // Workspace layout (~29.3 MB).
    uint2* xb            = (uint2*)d_ws;                       // 1,600,000 uint2 (12.8 MB)
    unsigned short* b_pk = (unsigned short*)(xb + 1600000);    // 65,536 bf16 (128 KB)
    float* b1p    = (float*)(b_pk + 65536);                    // 512
    float* w2p    = b1p + 512;                                 // 512
    float* zd     = w2p + 512;                                 // 50000
    int* deg      = (int*)(zd + N_NODES);                      // 50000
    int* rank     = deg + N_NODES;                             // 800000
    int* csrp     = rank + N_EDGES;                            // 3,200,000 (12.8 MB)

    hipMemsetAsync(deg, 0, N_NODES * sizeof(int), stream);

    k_rank<<<RB8 + XB + 33, 256, 0, stream>>>(dst, x, W1, b1, W2, deg, rank,
                                              xb, b_pk, b1p, w2p);
    k_fill<<<FB, 256, 0, stream>>>(src, dst, rank, csrp);
    k_gcn1<<<NTILES, 256, 0, stream>>>((const uint4*)xb, csrp, deg,
                                       b_pk, b1p, w2p, zd);
    k_gz  <<<NTILES, 256, 0, stream>>>(csrp, deg, zd, b2, out);
}